// Round 2
// baseline (564.056 us; speedup 1.0000x reference)
//
#include <hip/hip_runtime.h>

typedef unsigned short u16;
typedef short s16x8 __attribute__((ext_vector_type(8)));
typedef float f32x4 __attribute__((ext_vector_type(4)));
typedef u16 u16x4 __attribute__((ext_vector_type(4)));

#define NN 50000
#define NE 300000
#define HH 256
#define NCHUNK 196   // 196*256 >= 50000

__device__ __forceinline__ float b2f(u16 u) {
  union { float f; unsigned int i; } v; v.i = ((unsigned int)u) << 16; return v.f;
}
__device__ __forceinline__ u16 f2b(float f) {
  union { float f; unsigned int i; } v; v.f = f;
  unsigned int u = v.i;
  unsigned int r = (u + 0x7fffu + ((u >> 16) & 1u)) >> 16;
  return (u16)r;
}
__device__ __forceinline__ float lrelu(float x) { return x > 0.f ? x : 0.2f * x; }
__device__ __forceinline__ float waveAllSum(float v) {
#pragma unroll
  for (int o = 32; o > 0; o >>= 1) v += __shfl_xor(v, o);
  return v;
}

#define GLOAD_LDS16(SRC, DST)                                                   \
  __builtin_amdgcn_global_load_lds(                                             \
      (const __attribute__((address_space(1))) void*)(SRC),                     \
      (__attribute__((address_space(3))) void*)(DST), 16, 0, 0)

// ---------------------------------------------------------------------------
// f32 -> bf16 bulk convert (4 elems/thread)
__global__ void x2b_kernel(const float* __restrict__ x, u16* __restrict__ xb) {
  int i = blockIdx.x * 256 + threadIdx.x;
  if (i < NN * HH / 4) {
    f32x4 v = ((const f32x4*)x)[i];
    u16x4 o;
#pragma unroll
    for (int k = 0; k < 4; ++k) o[k] = f2b(v[k]);
    ((u16x4*)xb)[i] = o;
  }
}

// Transpose 256x256: dst[n][k] = bf16(src[k][n]); src f32, dst bf16
__global__ void transpose256(const float* __restrict__ src, u16* __restrict__ dst) {
  __shared__ float tile[32][33];
  int tx = threadIdx.x, ty = threadIdx.y;  // (32,8)
  int bx = blockIdx.x, by = blockIdx.y;    // (8,8)
#pragma unroll
  for (int j = 0; j < 32; j += 8)
    tile[ty + j][tx] = src[(size_t)(by * 32 + ty + j) * 256 + bx * 32 + tx];
  __syncthreads();
#pragma unroll
  for (int j = 0; j < 32; j += 8)
    dst[(size_t)(bx * 32 + ty + j) * 256 + by * 32 + tx] = f2b(tile[tx][ty + j]);
}

// ---------------------------------------------------------------------------
// Column mean accumulation: g_sum[c] += sum_r x[r][c]  (x f32)
__global__ void colmean(const float* __restrict__ x, float* __restrict__ g_sum) {
  int t = threadIdx.x;           // 256
  int b = blockIdx.x;            // 256
  float p = 0.f;
  for (int r = b; r < NN; r += 256) p += x[(size_t)r * HH + t];
  atomicAdd(&g_sum[t], p);
}

// Selector MLP (all f32): sw = softmax(relu(g@W1+b1)@W2+b2), g = g_sum/NN
__global__ void selector_kernel(const float* __restrict__ g_sum,
                                const float* __restrict__ W1, const float* __restrict__ b1,
                                const float* __restrict__ W2, const float* __restrict__ b2,
                                float* __restrict__ sw) {
  __shared__ float gg[256];
  __shared__ float hid[128];
  __shared__ float lg[4];
  int t = threadIdx.x;  // 128 threads
  gg[t] = g_sum[t] * (1.0f / NN);
  gg[t + 128] = g_sum[t + 128] * (1.0f / NN);
  __syncthreads();
  float a = 0.f;
  for (int c = 0; c < 256; ++c) a += gg[c] * W1[c * 128 + t];
  a += b1[t];
  hid[t] = a > 0.f ? a : 0.f;
  __syncthreads();
  if (t < 4) {
    float s = 0.f;
    for (int j = 0; j < 128; ++j) s += hid[j] * W2[j * 4 + t];
    lg[t] = s + b2[t];
  }
  __syncthreads();
  if (t == 0) {
    float m = fmaxf(fmaxf(lg[0], lg[1]), fmaxf(lg[2], lg[3]));
    float e0 = __expf(lg[0] - m), e1 = __expf(lg[1] - m);
    float e2 = __expf(lg[2] - m), e3 = __expf(lg[3] - m);
    float inv = 1.0f / (e0 + e1 + e2 + e3);
    sw[0] = e0 * inv; sw[1] = e1 * inv; sw[2] = e2 * inv; sw[3] = e3 * inv;
  }
}

// ---------------------------------------------------------------------------
// int64-vs-int32 detection: node ids < 2^31 => int64 arrays have all-zero odd words
__global__ void detect_kernel(const int* __restrict__ ei_raw, int* __restrict__ flag) {
  int t = threadIdx.x;  // 256
  int nz = 0;
  for (int k = t; k < 1024; k += 256) nz |= (ei_raw[2 * k + 1] != 0);
  if (nz) atomicOr(flag, 1);   // 1 => int32 layout
}

__global__ void norm_edges(const int* __restrict__ ei_raw, const int* __restrict__ ea_raw,
                           const int* __restrict__ flag, int* __restrict__ srcE,
                           int* __restrict__ dstE, int* __restrict__ attrE) {
  int e = blockIdx.x * 256 + threadIdx.x;
  if (e >= NE) return;
  if (*flag) {  // int32
    srcE[e] = ei_raw[e];
    dstE[e] = ei_raw[NE + e];
    attrE[e] = ea_raw[e];
  } else {      // int64 little-endian: low word at 2*idx
    srcE[e] = ei_raw[2 * e];
    dstE[e] = ei_raw[2 * NE + 2 * e];
    attrE[e] = ea_raw[2 * e];
  }
}

// ---------------------------------------------------------------------------
// CSR build: histogram, 3-stage scan, scatter (edge lists hold SRC node ids)
__global__ void hist_kernel(const int* __restrict__ dstE, const int* __restrict__ attrE,
                            int* __restrict__ counts) {
  int e = blockIdx.x * 256 + threadIdx.x;
  if (e < NE) {
    int a = attrE[e];
    if ((unsigned)a < 3u) atomicAdd(&counts[a * NN + dstE[e]], 1);
  }
}

__global__ void scan1(const int* __restrict__ counts, int* __restrict__ offs,
                      int* __restrict__ bsum) {
  int b = blockIdx.y, c = blockIdx.x, t = threadIdx.x;
  int idx = c * 256 + t;
  int v = (idx < NN) ? counts[b * NN + idx] : 0;
  __shared__ int sh[256];
  sh[t] = v;
  __syncthreads();
  for (int o = 1; o < 256; o <<= 1) {
    int add = (t >= o) ? sh[t - o] : 0;
    __syncthreads();
    sh[t] += add;
    __syncthreads();
  }
  int incl = sh[t];
  if (idx < NN) offs[b * (NN + 1) + idx] = incl - v;
  if (t == 255) bsum[b * NCHUNK + c] = incl;
}

__global__ void scan2(const int* __restrict__ bsum, int* __restrict__ bpre,
                      int* __restrict__ offs) {
  int t = threadIdx.x;
  if (t < 3) {
    int run = 0;
    for (int c = 0; c < NCHUNK; ++c) { bpre[t * NCHUNK + c] = run; run += bsum[t * NCHUNK + c]; }
    offs[t * (NN + 1) + NN] = run;
  }
}

__global__ void scan3(const int* __restrict__ bpre, int* __restrict__ offs,
                      int* __restrict__ cur) {
  int b = blockIdx.y, c = blockIdx.x;
  int idx = c * 256 + threadIdx.x;
  if (idx < NN) {
    int val = offs[b * (NN + 1) + idx] + bpre[b * NCHUNK + c];
    offs[b * (NN + 1) + idx] = val;
    cur[b * NN + idx] = val;
  }
}

__global__ void scatter_kernel(const int* __restrict__ srcE, const int* __restrict__ dstE,
                               const int* __restrict__ attrE, int* __restrict__ cur,
                               int* __restrict__ elist) {
  int e = blockIdx.x * 256 + threadIdx.x;
  if (e < NE) {
    int a = attrE[e];
    if ((unsigned)a < 3u) {
      int p = atomicAdd(&cur[a * NN + dstE[e]], 1);
      elist[a * NE + p] = srcE[e];
    }
  }
}

// ---------------------------------------------------------------------------
// GEMM: C[M,256] = A[M,256] @ B  (A,BT bf16; BT = B^T row-major [N][K]),
// C bf16 out, optional f32 bias (len 256). BM=BN=128, BK=64, 4 waves,
// mfma 16x16x32 bf16, global_load_lds staging with T2 XOR swizzle.
__global__ __launch_bounds__(256) void gemm_bt(const u16* __restrict__ A,
                                               const u16* __restrict__ BT,
                                               const float* __restrict__ bias,
                                               u16* __restrict__ C, int M) {
  const int K = 256, N = 256;
  __shared__ __align__(16) u16 lds_a[128 * 64];
  __shared__ __align__(16) u16 lds_b[128 * 64];
  int tid = threadIdx.x, lane = tid & 63, wid = tid >> 6;
  int wr = wid >> 1, wc = wid & 1;
  int row0 = blockIdx.x * 128, col0 = blockIdx.y * 128;

  f32x4 acc[4][4] = {};

  for (int k0 = 0; k0 < K; k0 += 64) {
    __syncthreads();  // protect LDS from previous iteration's readers
#pragma unroll
    for (int j = 0; j < 4; ++j) {
      int wbase = (j * 4 + wid) * 1024;     // wave-uniform byte base in 16KB tile
      int off = wbase + lane * 16;          // this lane's dest byte (linear)
      int r = off >> 7;                     // tile row (128B per row)
      int cb = off & 127;                   // byte within row
      int cbs = cb ^ ((r & 7) << 4);        // inverse swizzle on SOURCE (rule #21)
      int ga = row0 + r; if (ga > M - 1) ga = M - 1;
      const u16* srcA = A + (size_t)ga * K + k0 + (cbs >> 1);
      GLOAD_LDS16(srcA, (char*)lds_a + wbase);
      const u16* srcB = BT + (size_t)(col0 + r) * K + k0 + (cbs >> 1);
      GLOAD_LDS16(srcB, (char*)lds_b + wbase);
    }
    __syncthreads();
#pragma unroll
    for (int kk = 0; kk < 2; ++kk) {
      s16x8 af[4], bfr[4];
      int kb = kk * 64 + (lane >> 4) * 16;  // byte offset in 128B row
#pragma unroll
      for (int i = 0; i < 4; ++i) {
        int rowA = wr * 64 + i * 16 + (lane & 15);
        af[i] = *(const s16x8*)((const char*)lds_a + rowA * 128 + (kb ^ ((rowA & 7) << 4)));
        int rowB = wc * 64 + i * 16 + (lane & 15);
        bfr[i] = *(const s16x8*)((const char*)lds_b + rowB * 128 + (kb ^ ((rowB & 7) << 4)));
      }
#pragma unroll
      for (int i = 0; i < 4; ++i)
#pragma unroll
        for (int n = 0; n < 4; ++n)
          acc[i][n] = __builtin_amdgcn_mfma_f32_16x16x32_bf16(af[i], bfr[n], acc[i][n], 0, 0, 0);
    }
  }
#pragma unroll
  for (int i = 0; i < 4; ++i) {
#pragma unroll
    for (int n = 0; n < 4; ++n) {
      int col = col0 + wc * 64 + n * 16 + (lane & 15);
      float badd = bias ? bias[col] : 0.0f;
#pragma unroll
      for (int r = 0; r < 4; ++r) {
        int row = row0 + wr * 64 + i * 16 + (lane >> 4) * 4 + r;
        if (row < M) C[(size_t)row * N + col] = f2b(acc[i][n][r] + badd);
      }
    }
  }
}

// ---------------------------------------------------------------------------
// s[v] = h[v]·a_src, d[v] = h[v]·a_dst  (h bf16, a f32; one wave per row)
__global__ void sd_kernel(const u16* __restrict__ h, const float* __restrict__ av,
                          const float* __restrict__ dv, float* __restrict__ s,
                          float* __restrict__ d) {
  int v = blockIdx.x * 4 + (threadIdx.x >> 6);
  int lane = threadIdx.x & 63;
  u16x4 hv = *(const u16x4*)(h + (size_t)v * HH + lane * 4);
  f32x4 a4 = *(const f32x4*)(av + lane * 4);
  f32x4 d4 = *(const f32x4*)(dv + lane * 4);
  float ps = 0.f, pd = 0.f;
#pragma unroll
  for (int k = 0; k < 4; ++k) {
    float f = b2f(hv[k]);
    ps += f * a4[k];
    pd += f * d4[k];
  }
  ps = waveAllSum(ps);
  pd = waveAllSum(pd);
  if (lane == 0) { s[v] = ps; d[v] = pd; }
}

// GAT aggregation: xi[v] = (sum_e w_e h[src_e] + w_self h[v]) / denom + bg  (bf16 out)
__global__ void gat_agg(const int* __restrict__ offs_b, const int* __restrict__ elist_b,
                        const float* __restrict__ s, const float* __restrict__ d,
                        const u16* __restrict__ h, const float* __restrict__ bgrow,
                        u16* __restrict__ xi) {
  int v = blockIdx.x * 4 + (threadIdx.x >> 6);
  int lane = threadIdx.x & 63;
  float dv = d[v], sv = s[v];
  float eself = lrelu(sv + dv);
  int beg = offs_b[v], end = offs_b[v + 1];
  float m = eself;
  for (int j = beg; j < end; ++j) m = fmaxf(m, lrelu(s[elist_b[j]] + dv));
  float denom = 0.f;
  float acc[4] = {0.f, 0.f, 0.f, 0.f};
  for (int j = beg; j < end; ++j) {
    int u = elist_b[j];
    float w = __expf(lrelu(s[u] + dv) - m);
    denom += w;
    u16x4 hv = *(const u16x4*)(h + (size_t)u * HH + lane * 4);
#pragma unroll
    for (int k = 0; k < 4; ++k) acc[k] += w * b2f(hv[k]);
  }
  float wself = __expf(eself - m);
  denom += wself;
  u16x4 hv = *(const u16x4*)(h + (size_t)v * HH + lane * 4);
#pragma unroll
  for (int k = 0; k < 4; ++k) acc[k] += wself * b2f(hv[k]);
  float inv = 1.0f / denom;
  f32x4 bg4 = *(const f32x4*)(bgrow + lane * 4);
  u16x4 outv;
#pragma unroll
  for (int k = 0; k < 4; ++k) outv[k] = f2b(acc[k] * inv + bg4[k]);
  *(u16x4*)(xi + (size_t)v * HH + lane * 4) = outv;
}

// combined += sw[i] * relu(LN(y)); y bf16, gains/biases f32, comb bf16 rmw
__global__ void ln_accum(const u16* __restrict__ y, const float* __restrict__ gv,
                         const float* __restrict__ bv, const float* __restrict__ sw,
                         int swidx, u16* __restrict__ comb) {
  int v = blockIdx.x * 4 + (threadIdx.x >> 6);
  int lane = threadIdx.x & 63;
  u16x4 yv = *(const u16x4*)(y + (size_t)v * HH + lane * 4);
  float f[4];
  float ls = 0.f, lq = 0.f;
#pragma unroll
  for (int k = 0; k < 4; ++k) { f[k] = b2f(yv[k]); ls += f[k]; lq += f[k] * f[k]; }
  ls = waveAllSum(ls);
  lq = waveAllSum(lq);
  float mu = ls * (1.0f / HH);
  float var = lq * (1.0f / HH) - mu * mu;
  float rs = rsqrtf(var + 1e-5f);
  float w = sw[swidx];
  f32x4 gvv = *(const f32x4*)(gv + lane * 4);
  f32x4 bvv = *(const f32x4*)(bv + lane * 4);
  u16x4 cv = *(u16x4*)(comb + (size_t)v * HH + lane * 4);
  u16x4 outv;
#pragma unroll
  for (int k = 0; k < 4; ++k) {
    float t = (f[k] - mu) * rs * gvv[k] + bvv[k];
    t = t > 0.f ? t : 0.f;
    outv[k] = f2b(b2f(cv[k]) + w * t);
  }
  *(u16x4*)(comb + (size_t)v * HH + lane * 4) = outv;
}

// out = relu(LN(z)) ; z bf16, out f32
__global__ void ln_out(const u16* __restrict__ z, const float* __restrict__ gv,
                       const float* __restrict__ bv, float* __restrict__ out) {
  int v = blockIdx.x * 4 + (threadIdx.x >> 6);
  int lane = threadIdx.x & 63;
  u16x4 zv = *(const u16x4*)(z + (size_t)v * HH + lane * 4);
  float f[4];
  float ls = 0.f, lq = 0.f;
#pragma unroll
  for (int k = 0; k < 4; ++k) { f[k] = b2f(zv[k]); ls += f[k]; lq += f[k] * f[k]; }
  ls = waveAllSum(ls);
  lq = waveAllSum(lq);
  float mu = ls * (1.0f / HH);
  float var = lq * (1.0f / HH) - mu * mu;
  float rs = rsqrtf(var + 1e-5f);
  f32x4 gvv = *(const f32x4*)(gv + lane * 4);
  f32x4 bvv = *(const f32x4*)(bv + lane * 4);
  f32x4 outv;
#pragma unroll
  for (int k = 0; k < 4; ++k) {
    float t = (f[k] - mu) * rs * gvv[k] + bvv[k];
    outv[k] = t > 0.f ? t : 0.f;
  }
  *(f32x4*)(out + (size_t)v * HH + lane * 4) = outv;
}

// ---------------------------------------------------------------------------
extern "C" void kernel_launch(void* const* d_in, const int* in_sizes, int n_in,
                              void* d_out, int out_size, void* d_ws, size_t ws_size,
                              hipStream_t stream) {
  const float* x   = (const float*)d_in[0];
  const int* ei    = (const int*)d_in[1];   // [2][NE] (int32 or int64 -- detected)
  const int* ea    = (const int*)d_in[2];   // [NE]
  const float* Wg  = (const float*)d_in[3]; // [3][256][256]
  const float* asrc= (const float*)d_in[4]; // [3][256]
  const float* adst= (const float*)d_in[5];
  const float* bg  = (const float*)d_in[6];
  const float* Wsm = (const float*)d_in[7]; // [4][256][256]
  const float* bs  = (const float*)d_in[8];
  const float* gs  = (const float*)d_in[9];
  const float* betas=(const float*)d_in[10];
  const float* W1  = (const float*)d_in[11];// [256][128]
  const float* b1  = (const float*)d_in[12];
  const float* W2  = (const float*)d_in[13];// [128][4]
  const float* b2  = (const float*)d_in[14];
  const float* Wf  = (const float*)d_in[15];// [256][256]
  const float* bfv = (const float*)d_in[16];
  const float* gf  = (const float*)d_in[17];
  const float* betaf=(const float*)d_in[18];
  float* out = (float*)d_out;

  char* wsb = (char*)d_ws;
  size_t off = 0;
  auto alloc = [&](size_t bytes) -> void* {
    void* p = wsb + off;
    off += bytes;
    off = (off + 255) & ~(size_t)255;
    return p;
  };
  int* flag    = (int*)alloc(sizeof(int));
  float* g_sum = (float*)alloc(256 * sizeof(float));
  float* sw    = (float*)alloc(4 * sizeof(float));
  int* counts  = (int*)alloc((size_t)3 * NN * sizeof(int));
  int* offs    = (int*)alloc((size_t)3 * (NN + 1) * sizeof(int));
  int* cur     = (int*)alloc((size_t)3 * NN * sizeof(int));
  int* bsum    = (int*)alloc((size_t)3 * NCHUNK * sizeof(int));
  int* bpre    = (int*)alloc((size_t)3 * NCHUNK * sizeof(int));
  int* srcE    = (int*)alloc((size_t)NE * sizeof(int));
  int* dstE    = (int*)alloc((size_t)NE * sizeof(int));
  int* attrE   = (int*)alloc((size_t)NE * sizeof(int));
  int* elist   = (int*)alloc((size_t)3 * NE * sizeof(int));
  float* s_arr = (float*)alloc((size_t)NN * sizeof(float));
  float* d_arr = (float*)alloc((size_t)NN * sizeof(float));
  u16* WT      = (u16*)alloc((size_t)8 * 65536 * sizeof(u16));  // WgT0-2, WsT0-3, WfT (bf16)
  u16* xb      = (u16*)alloc((size_t)NN * HH * sizeof(u16));    // x in bf16
  u16* hbuf    = (u16*)alloc((size_t)NN * HH * sizeof(u16));    // h / y / z
  u16* xibuf   = (u16*)alloc((size_t)NN * HH * sizeof(u16));
  u16* comb    = (u16*)alloc((size_t)NN * HH * sizeof(u16));
  (void)ws_size; (void)in_sizes; (void)n_in; (void)out_size;

  hipMemsetAsync(flag, 0, sizeof(int), stream);
  hipMemsetAsync(g_sum, 0, 256 * sizeof(float), stream);
  hipMemsetAsync(counts, 0, (size_t)3 * NN * sizeof(int), stream);
  hipMemsetAsync(comb, 0, (size_t)NN * HH * sizeof(u16), stream);

  // edge dtype normalization
  detect_kernel<<<1, 256, 0, stream>>>(ei, flag);
  norm_edges<<<(NE + 255) / 256, 256, 0, stream>>>(ei, ea, flag, srcE, dstE, attrE);

  // weight transposes (f32 -> bf16)
  dim3 tb(32, 8), tg(8, 8);
  const float* tsrc[8] = {Wg, Wg + 65536, Wg + 131072,
                          Wsm, Wsm + 65536, Wsm + 131072, Wsm + 196608, Wf};
  for (int i = 0; i < 8; ++i)
    transpose256<<<tg, tb, 0, stream>>>(tsrc[i], WT + (size_t)i * 65536);

  x2b_kernel<<<(NN * HH / 4 + 255) / 256, 256, 0, stream>>>(x, xb);
  colmean<<<256, 256, 0, stream>>>(x, g_sum);
  selector_kernel<<<1, 128, 0, stream>>>(g_sum, W1, b1, W2, b2, sw);

  hist_kernel<<<(NE + 255) / 256, 256, 0, stream>>>(dstE, attrE, counts);
  scan1<<<dim3(NCHUNK, 3), 256, 0, stream>>>(counts, offs, bsum);
  scan2<<<1, 64, 0, stream>>>(bsum, bpre, offs);
  scan3<<<dim3(NCHUNK, 3), 256, 0, stream>>>(bpre, offs, cur);
  scatter_kernel<<<(NE + 255) / 256, 256, 0, stream>>>(srcE, dstE, attrE, cur, elist);

  dim3 gemm_grid((NN + 127) / 128, 2);
  for (int i = 0; i < 3; ++i) {
    gemm_bt<<<gemm_grid, 256, 0, stream>>>(xb, WT + (size_t)i * 65536, nullptr, hbuf, NN);
    sd_kernel<<<12500, 256, 0, stream>>>(hbuf, asrc + i * 256, adst + i * 256, s_arr, d_arr);
    gat_agg<<<12500, 256, 0, stream>>>(offs + (size_t)i * (NN + 1), elist + (size_t)i * NE,
                                       s_arr, d_arr, hbuf, bg + i * 256, xibuf);
    gemm_bt<<<gemm_grid, 256, 0, stream>>>(xibuf, WT + (size_t)(3 + i) * 65536,
                                           bs + i * 256, hbuf, NN);
    ln_accum<<<12500, 256, 0, stream>>>(hbuf, gs + i * 256, betas + i * 256, sw, i, comb);
  }
  // branch 3: identity GAT
  gemm_bt<<<gemm_grid, 256, 0, stream>>>(xb, WT + (size_t)6 * 65536, bs + 3 * 256, hbuf, NN);
  ln_accum<<<12500, 256, 0, stream>>>(hbuf, gs + 3 * 256, betas + 3 * 256, sw, 3, comb);
  // fusion
  gemm_bt<<<gemm_grid, 256, 0, stream>>>(comb, WT + (size_t)7 * 65536, bfv, hbuf, NN);
  ln_out<<<12500, 256, 0, stream>>>(hbuf, gf, betaf, out);
}

// Round 3
// 462.248 us; speedup vs baseline: 1.2202x; 1.2202x over previous
//
#include <hip/hip_runtime.h>

typedef unsigned short u16;
typedef short s16x8 __attribute__((ext_vector_type(8)));
typedef float f32x4 __attribute__((ext_vector_type(4)));
typedef u16 u16x4 __attribute__((ext_vector_type(4)));

#define NN 50000
#define NE 300000
#define HH 256
#define NCHUNK 196   // 196*256 >= 50000

__device__ __forceinline__ float b2f(u16 u) {
  union { float f; unsigned int i; } v; v.i = ((unsigned int)u) << 16; return v.f;
}
__device__ __forceinline__ u16 f2b(float f) {
  union { float f; unsigned int i; } v; v.f = f;
  unsigned int u = v.i;
  unsigned int r = (u + 0x7fffu + ((u >> 16) & 1u)) >> 16;
  return (u16)r;
}
__device__ __forceinline__ float lrelu(float x) { return x > 0.f ? x : 0.2f * x; }

#define GLOAD_LDS16(SRC, DST)                                                   \
  __builtin_amdgcn_global_load_lds(                                             \
      (const __attribute__((address_space(1))) void*)(SRC),                     \
      (__attribute__((address_space(3))) void*)(DST), 16, 0, 0)

// ---------------------------------------------------------------------------
// Fused: xb = bf16(x), g_sum[c] += column sums (vectorized f32x4, block reduce)
__global__ void xprep(const float* __restrict__ x, u16* __restrict__ xb,
                      float* __restrict__ g_sum) {
  int tid = threadIdx.x, lane = tid & 63, w = tid >> 6;
  f32x4 part = {0.f, 0.f, 0.f, 0.f};
  for (int r = blockIdx.x * 4 + w; r < NN; r += 1024) {
    f32x4 v = *(const f32x4*)(x + (size_t)r * HH + lane * 4);
    u16x4 o;
#pragma unroll
    for (int k = 0; k < 4; ++k) o[k] = f2b(v[k]);
    *(u16x4*)(xb + (size_t)r * HH + lane * 4) = o;
    part += v;
  }
  __shared__ f32x4 sh[256];
  sh[tid] = part;
  __syncthreads();
  if (tid < 64) {
    f32x4 t = sh[tid] + sh[tid + 64] + sh[tid + 128] + sh[tid + 192];
#pragma unroll
    for (int k = 0; k < 4; ++k) atomicAdd(&g_sum[lane * 4 + k], t[k]);
  }
}

// All 8 weight transposes in one launch: dst[n][k] = bf16(src[k][n])
__global__ void transpose_all(const float* __restrict__ Wg, const float* __restrict__ Wsm,
                              const float* __restrict__ Wf, u16* __restrict__ WT) {
  __shared__ float tile[32][33];
  int z = blockIdx.z;
  const float* src = (z < 3) ? (Wg + (size_t)z * 65536)
                   : (z < 7) ? (Wsm + (size_t)(z - 3) * 65536) : Wf;
  u16* dst = WT + (size_t)z * 65536;
  int tx = threadIdx.x, ty = threadIdx.y;  // (32,8)
  int bx = blockIdx.x, by = blockIdx.y;    // (8,8)
#pragma unroll
  for (int j = 0; j < 32; j += 8)
    tile[ty + j][tx] = src[(size_t)(by * 32 + ty + j) * 256 + bx * 32 + tx];
  __syncthreads();
#pragma unroll
  for (int j = 0; j < 32; j += 8)
    dst[(size_t)(bx * 32 + ty + j) * 256 + by * 32 + tx] = f2b(tile[tx][ty + j]);
}

// Selector MLP (f32): sw = softmax(relu(g@W1+b1)@W2+b2), g = g_sum/NN
__global__ void selector_kernel(const float* __restrict__ g_sum,
                                const float* __restrict__ W1, const float* __restrict__ b1,
                                const float* __restrict__ W2, const float* __restrict__ b2,
                                float* __restrict__ sw) {
  __shared__ float gg[256];
  __shared__ float hid[128];
  __shared__ float lg[4];
  int t = threadIdx.x;  // 128 threads
  gg[t] = g_sum[t] * (1.0f / NN);
  gg[t + 128] = g_sum[t + 128] * (1.0f / NN);
  __syncthreads();
  float a = 0.f;
  for (int c = 0; c < 256; ++c) a += gg[c] * W1[c * 128 + t];
  a += b1[t];
  hid[t] = a > 0.f ? a : 0.f;
  __syncthreads();
  if (t < 4) {
    float s = 0.f;
    for (int j = 0; j < 128; ++j) s += hid[j] * W2[j * 4 + t];
    lg[t] = s + b2[t];
  }
  __syncthreads();
  if (t == 0) {
    float m = fmaxf(fmaxf(lg[0], lg[1]), fmaxf(lg[2], lg[3]));
    float e0 = __expf(lg[0] - m), e1 = __expf(lg[1] - m);
    float e2 = __expf(lg[2] - m), e3 = __expf(lg[3] - m);
    float inv = 1.0f / (e0 + e1 + e2 + e3);
    sw[0] = e0 * inv; sw[1] = e1 * inv; sw[2] = e2 * inv; sw[3] = e3 * inv;
  }
}

// ---------------------------------------------------------------------------
// int64-vs-int32 detection + edge normalization
__global__ void detect_kernel(const int* __restrict__ ei_raw, int* __restrict__ flag) {
  int t = threadIdx.x;
  int nz = 0;
  for (int k = t; k < 1024; k += 256) nz |= (ei_raw[2 * k + 1] != 0);
  if (nz) atomicOr(flag, 1);   // 1 => int32 layout
}

__global__ void norm_edges(const int* __restrict__ ei_raw, const int* __restrict__ ea_raw,
                           const int* __restrict__ flag, int* __restrict__ srcE,
                           int* __restrict__ dstE, int* __restrict__ attrE) {
  int e = blockIdx.x * 256 + threadIdx.x;
  if (e >= NE) return;
  if (*flag) {
    srcE[e] = ei_raw[e];
    dstE[e] = ei_raw[NE + e];
    attrE[e] = ea_raw[e];
  } else {
    srcE[e] = ei_raw[2 * e];
    dstE[e] = ei_raw[2 * NE + 2 * e];
    attrE[e] = ea_raw[2 * e];
  }
}

// ---------------------------------------------------------------------------
// CSR build
__global__ void hist_kernel(const int* __restrict__ dstE, const int* __restrict__ attrE,
                            int* __restrict__ counts) {
  int e = blockIdx.x * 256 + threadIdx.x;
  if (e < NE) {
    int a = attrE[e];
    if ((unsigned)a < 3u) atomicAdd(&counts[a * NN + dstE[e]], 1);
  }
}

__global__ void scan1(const int* __restrict__ counts, int* __restrict__ offs,
                      int* __restrict__ bsum) {
  int b = blockIdx.y, c = blockIdx.x, t = threadIdx.x;
  int idx = c * 256 + t;
  int v = (idx < NN) ? counts[b * NN + idx] : 0;
  __shared__ int sh[256];
  sh[t] = v;
  __syncthreads();
  for (int o = 1; o < 256; o <<= 1) {
    int add = (t >= o) ? sh[t - o] : 0;
    __syncthreads();
    sh[t] += add;
    __syncthreads();
  }
  int incl = sh[t];
  if (idx < NN) offs[b * (NN + 1) + idx] = incl - v;
  if (t == 255) bsum[b * NCHUNK + c] = incl;
}

__global__ void scan2(const int* __restrict__ bsum, int* __restrict__ bpre,
                      int* __restrict__ offs) {
  int t = threadIdx.x;
  if (t < 3) {
    int run = 0;
    for (int c = 0; c < NCHUNK; ++c) { bpre[t * NCHUNK + c] = run; run += bsum[t * NCHUNK + c]; }
    offs[t * (NN + 1) + NN] = run;
  }
}

__global__ void scan3(const int* __restrict__ bpre, int* __restrict__ offs,
                      int* __restrict__ cur) {
  int b = blockIdx.y, c = blockIdx.x;
  int idx = c * 256 + threadIdx.x;
  if (idx < NN) {
    int val = offs[b * (NN + 1) + idx] + bpre[b * NCHUNK + c];
    offs[b * (NN + 1) + idx] = val;
    cur[b * NN + idx] = val;
  }
}

__global__ void scatter_kernel(const int* __restrict__ srcE, const int* __restrict__ dstE,
                               const int* __restrict__ attrE, int* __restrict__ cur,
                               int* __restrict__ elist) {
  int e = blockIdx.x * 256 + threadIdx.x;
  if (e < NE) {
    int a = attrE[e];
    if ((unsigned)a < 3u) {
      int p = atomicAdd(&cur[a * NN + dstE[e]], 1);
      elist[a * NE + p] = srcE[e];
    }
  }
}

// ---------------------------------------------------------------------------
// GEMM C[M,256] = A[M,256]@B, BT=B^T [256][256] bf16. BM=64, BN=256, BK=64,
// 4 waves (wave wc owns cols wc*64..+63). Fused epilogues:
//   EPI=0: write C bf16 + per-row dots s=h·a_src, d=h·a_dst
//   EPI=1: comb[row] (+)= sw[swidx]*relu(LN(acc+bias)) (init => overwrite)
//   EPI=2: outf[row] = relu(LN(acc+bias))  (f32)
template <int EPI>
__global__ __launch_bounds__(256) void gemm256(
    const u16* __restrict__ A, const u16* __restrict__ BT,
    const float* __restrict__ bias, u16* __restrict__ C, float* __restrict__ outf,
    const float* __restrict__ av, const float* __restrict__ dvec,
    float* __restrict__ s_arr, float* __restrict__ d_arr,
    const float* __restrict__ gv, const float* __restrict__ betav,
    const float* __restrict__ sw, int swidx, u16* __restrict__ comb,
    int initFlag, int M) {
  const int K = 256;
  __shared__ __align__(16) u16 lds_a[64 * 64];    // 8KB
  __shared__ __align__(16) u16 lds_b[256 * 64];   // 32KB
  __shared__ float redS[4][64];
  __shared__ float redQ[4][64];
  __shared__ float muL[64];
  __shared__ float rsL[64];
  int tid = threadIdx.x, lane = tid & 63, wid = tid >> 6;
  int wc = wid;                       // wave column block
  int row0 = blockIdx.x * 64;

  f32x4 acc[4][4] = {};

  for (int k0 = 0; k0 < K; k0 += 64) {
    __syncthreads();
    // stage A tile (64x64): 2 rounds
#pragma unroll
    for (int j = 0; j < 2; ++j) {
      int off = j * 4096 + tid * 16;
      int r = off >> 7, cb = off & 127;
      int cbs = cb ^ ((r & 7) << 4);
      int ga = row0 + r; if (ga > M - 1) ga = M - 1;
      GLOAD_LDS16(A + (size_t)ga * K + k0 + (cbs >> 1),
                  (char*)lds_a + j * 4096 + wid * 1024);
    }
    // stage B tile (256x64): 8 rounds
#pragma unroll
    for (int j = 0; j < 8; ++j) {
      int off = j * 4096 + tid * 16;
      int r = off >> 7, cb = off & 127;
      int cbs = cb ^ ((r & 7) << 4);
      GLOAD_LDS16(BT + (size_t)r * K + k0 + (cbs >> 1),
                  (char*)lds_b + j * 4096 + wid * 1024);
    }
    __syncthreads();
#pragma unroll
    for (int kk = 0; kk < 2; ++kk) {
      s16x8 af[4], bfr[4];
      int kb = kk * 64 + (lane >> 4) * 16;
#pragma unroll
      for (int i = 0; i < 4; ++i) {
        int rowA = i * 16 + (lane & 15);
        af[i] = *(const s16x8*)((const char*)lds_a + rowA * 128 + (kb ^ ((rowA & 7) << 4)));
        int rowB = wc * 64 + i * 16 + (lane & 15);
        bfr[i] = *(const s16x8*)((const char*)lds_b + rowB * 128 + (kb ^ ((rowB & 7) << 4)));
      }
#pragma unroll
      for (int i = 0; i < 4; ++i)
#pragma unroll
        for (int n = 0; n < 4; ++n)
          acc[i][n] = __builtin_amdgcn_mfma_f32_16x16x32_bf16(af[i], bfr[n], acc[i][n], 0, 0, 0);
    }
  }

  // ---- epilogue ----
  int colbase = wc * 64 + (lane & 15);
  if (EPI == 0) {
    // h write + per-row dots with a_src/a_dst
    float a4[4], dd4[4];
#pragma unroll
    for (int n = 0; n < 4; ++n) { a4[n] = av[colbase + n * 16]; dd4[n] = dvec[colbase + n * 16]; }
#pragma unroll
    for (int i = 0; i < 4; ++i)
#pragma unroll
      for (int r = 0; r < 4; ++r) {
        float sp = 0.f, dp = 0.f;
#pragma unroll
        for (int n = 0; n < 4; ++n) { float v = acc[i][n][r]; sp += v * a4[n]; dp += v * dd4[n]; }
#pragma unroll
        for (int m = 1; m < 16; m <<= 1) { sp += __shfl_xor(sp, m); dp += __shfl_xor(dp, m); }
        if ((lane & 15) == 0) {
          int rl = i * 16 + (lane >> 4) * 4 + r;
          redS[wc][rl] = sp; redQ[wc][rl] = dp;
        }
      }
    __syncthreads();
    if (tid < 64 && row0 + tid < M) {
      s_arr[row0 + tid] = redS[0][tid] + redS[1][tid] + redS[2][tid] + redS[3][tid];
      d_arr[row0 + tid] = redQ[0][tid] + redQ[1][tid] + redQ[2][tid] + redQ[3][tid];
    }
#pragma unroll
    for (int i = 0; i < 4; ++i)
#pragma unroll
      for (int r = 0; r < 4; ++r) {
        int row = row0 + i * 16 + (lane >> 4) * 4 + r;
        if (row < M)
#pragma unroll
          for (int n = 0; n < 4; ++n)
            C[(size_t)row * 256 + colbase + n * 16] = f2b(acc[i][n][r]);
      }
  } else {
    float bv4[4], g4[4], be4[4];
#pragma unroll
    for (int n = 0; n < 4; ++n) {
      bv4[n] = bias[colbase + n * 16];
      g4[n] = gv[colbase + n * 16];
      be4[n] = betav[colbase + n * 16];
    }
#pragma unroll
    for (int i = 0; i < 4; ++i)
#pragma unroll
      for (int n = 0; n < 4; ++n)
#pragma unroll
        for (int r = 0; r < 4; ++r) acc[i][n][r] += bv4[n];
    // row mean/var
#pragma unroll
    for (int i = 0; i < 4; ++i)
#pragma unroll
      for (int r = 0; r < 4; ++r) {
        float s = 0.f, q = 0.f;
#pragma unroll
        for (int n = 0; n < 4; ++n) { float v = acc[i][n][r]; s += v; q += v * v; }
#pragma unroll
        for (int m = 1; m < 16; m <<= 1) { s += __shfl_xor(s, m); q += __shfl_xor(q, m); }
        if ((lane & 15) == 0) {
          int rl = i * 16 + (lane >> 4) * 4 + r;
          redS[wc][rl] = s; redQ[wc][rl] = q;
        }
      }
    __syncthreads();
    if (tid < 64) {
      float s = redS[0][tid] + redS[1][tid] + redS[2][tid] + redS[3][tid];
      float q = redQ[0][tid] + redQ[1][tid] + redQ[2][tid] + redQ[3][tid];
      float mu = s * (1.0f / HH);
      float var = q * (1.0f / HH) - mu * mu;
      muL[tid] = mu;
      rsL[tid] = rsqrtf(var + 1e-5f);
    }
    __syncthreads();
    float w = (EPI == 1) ? sw[swidx] : 0.f;
#pragma unroll
    for (int i = 0; i < 4; ++i)
#pragma unroll
      for (int r = 0; r < 4; ++r) {
        int rl = i * 16 + (lane >> 4) * 4 + r;
        int row = row0 + rl;
        if (row >= M) continue;
        float mu = muL[rl], rs = rsL[rl];
#pragma unroll
        for (int n = 0; n < 4; ++n) {
          int col = colbase + n * 16;
          float t = (acc[i][n][r] - mu) * rs * g4[n] + be4[n];
          t = t > 0.f ? t : 0.f;
          if (EPI == 1) {
            float prev = initFlag ? 0.f : b2f(comb[(size_t)row * 256 + col]);
            comb[(size_t)row * 256 + col] = f2b(prev + w * t);
          } else {
            outf[(size_t)row * 256 + col] = t;
          }
        }
      }
  }
}

// ---------------------------------------------------------------------------
// GAT aggregation: xi[v] = (sum_e w_e h[src_e] + w_self h[v]) / denom + bg
__global__ void gat_agg(const int* __restrict__ offs_b, const int* __restrict__ elist_b,
                        const float* __restrict__ s, const float* __restrict__ d,
                        const u16* __restrict__ h, const float* __restrict__ bgrow,
                        u16* __restrict__ xi) {
  int v = blockIdx.x * 4 + (threadIdx.x >> 6);
  int lane = threadIdx.x & 63;
  float dv = d[v], sv = s[v];
  float eself = lrelu(sv + dv);
  int beg = offs_b[v], end = offs_b[v + 1];
  float m = eself;
  for (int j = beg; j < end; ++j) m = fmaxf(m, lrelu(s[elist_b[j]] + dv));
  float denom = 0.f;
  float acc[4] = {0.f, 0.f, 0.f, 0.f};
  for (int j = beg; j < end; ++j) {
    int u = elist_b[j];
    float w = __expf(lrelu(s[u] + dv) - m);
    denom += w;
    u16x4 hv = *(const u16x4*)(h + (size_t)u * HH + lane * 4);
#pragma unroll
    for (int k = 0; k < 4; ++k) acc[k] += w * b2f(hv[k]);
  }
  float wself = __expf(eself - m);
  denom += wself;
  u16x4 hv = *(const u16x4*)(h + (size_t)v * HH + lane * 4);
#pragma unroll
  for (int k = 0; k < 4; ++k) acc[k] += wself * b2f(hv[k]);
  float inv = 1.0f / denom;
  f32x4 bg4 = *(const f32x4*)(bgrow + lane * 4);
  u16x4 outv;
#pragma unroll
  for (int k = 0; k < 4; ++k) outv[k] = f2b(acc[k] * inv + bg4[k]);
  *(u16x4*)(xi + (size_t)v * HH + lane * 4) = outv;
}

// ---------------------------------------------------------------------------
extern "C" void kernel_launch(void* const* d_in, const int* in_sizes, int n_in,
                              void* d_out, int out_size, void* d_ws, size_t ws_size,
                              hipStream_t stream) {
  const float* x   = (const float*)d_in[0];
  const int* ei    = (const int*)d_in[1];
  const int* ea    = (const int*)d_in[2];
  const float* Wg  = (const float*)d_in[3];
  const float* asrc= (const float*)d_in[4];
  const float* adst= (const float*)d_in[5];
  const float* bg  = (const float*)d_in[6];
  const float* Wsm = (const float*)d_in[7];
  const float* bs  = (const float*)d_in[8];
  const float* gs  = (const float*)d_in[9];
  const float* betas=(const float*)d_in[10];
  const float* W1  = (const float*)d_in[11];
  const float* b1  = (const float*)d_in[12];
  const float* W2  = (const float*)d_in[13];
  const float* b2  = (const float*)d_in[14];
  const float* Wf  = (const float*)d_in[15];
  const float* bfv = (const float*)d_in[16];
  const float* gf  = (const float*)d_in[17];
  const float* betaf=(const float*)d_in[18];
  float* out = (float*)d_out;

  char* wsb = (char*)d_ws;
  size_t off = 0;
  auto alloc = [&](size_t bytes) -> void* {
    void* p = wsb + off;
    off += bytes;
    off = (off + 255) & ~(size_t)255;
    return p;
  };
  int* flag    = (int*)alloc(sizeof(int));
  float* g_sum = (float*)alloc(256 * sizeof(float));
  float* sw    = (float*)alloc(4 * sizeof(float));
  int* counts  = (int*)alloc((size_t)3 * NN * sizeof(int));
  int* offs    = (int*)alloc((size_t)3 * (NN + 1) * sizeof(int));
  int* cur     = (int*)alloc((size_t)3 * NN * sizeof(int));
  int* bsum    = (int*)alloc((size_t)3 * NCHUNK * sizeof(int));
  int* bpre    = (int*)alloc((size_t)3 * NCHUNK * sizeof(int));
  int* srcE    = (int*)alloc((size_t)NE * sizeof(int));
  int* dstE    = (int*)alloc((size_t)NE * sizeof(int));
  int* attrE   = (int*)alloc((size_t)NE * sizeof(int));
  int* elist   = (int*)alloc((size_t)3 * NE * sizeof(int));
  float* s_arr = (float*)alloc((size_t)NN * sizeof(float));
  float* d_arr = (float*)alloc((size_t)NN * sizeof(float));
  u16* WT      = (u16*)alloc((size_t)8 * 65536 * sizeof(u16));
  u16* xb      = (u16*)alloc((size_t)NN * HH * sizeof(u16));
  u16* hbuf    = (u16*)alloc((size_t)NN * HH * sizeof(u16));
  u16* xibuf   = (u16*)alloc((size_t)NN * HH * sizeof(u16));
  u16* comb    = (u16*)alloc((size_t)NN * HH * sizeof(u16));
  (void)ws_size; (void)in_sizes; (void)n_in; (void)out_size;

  hipMemsetAsync(flag, 0, sizeof(int), stream);
  hipMemsetAsync(g_sum, 0, 256 * sizeof(float), stream);
  hipMemsetAsync(counts, 0, (size_t)3 * NN * sizeof(int), stream);

  detect_kernel<<<1, 256, 0, stream>>>(ei, flag);
  norm_edges<<<(NE + 255) / 256, 256, 0, stream>>>(ei, ea, flag, srcE, dstE, attrE);

  transpose_all<<<dim3(8, 8, 8), dim3(32, 8), 0, stream>>>(Wg, Wsm, Wf, WT);
  xprep<<<256, 256, 0, stream>>>(x, xb, g_sum);
  selector_kernel<<<1, 128, 0, stream>>>(g_sum, W1, b1, W2, b2, sw);

  hist_kernel<<<(NE + 255) / 256, 256, 0, stream>>>(dstE, attrE, counts);
  scan1<<<dim3(NCHUNK, 3), 256, 0, stream>>>(counts, offs, bsum);
  scan2<<<1, 64, 0, stream>>>(bsum, bpre, offs);
  scan3<<<dim3(NCHUNK, 3), 256, 0, stream>>>(bpre, offs, cur);
  scatter_kernel<<<(NE + 255) / 256, 256, 0, stream>>>(srcE, dstE, attrE, cur, elist);

  const int GB = (NN + 63) / 64;  // 782 blocks

  // branch 3 first (identity input): init comb
  gemm256<1><<<GB, 256, 0, stream>>>(xb, WT + (size_t)6 * 65536, bs + 3 * 256,
                                     nullptr, nullptr, nullptr, nullptr, nullptr, nullptr,
                                     gs + 3 * 256, betas + 3 * 256, sw, 3, comb, 1, NN);
  for (int i = 0; i < 3; ++i) {
    gemm256<0><<<GB, 256, 0, stream>>>(xb, WT + (size_t)i * 65536, nullptr,
                                       hbuf, nullptr, asrc + i * 256, adst + i * 256,
                                       s_arr, d_arr, nullptr, nullptr, nullptr, 0, nullptr, 0, NN);
    gat_agg<<<12500, 256, 0, stream>>>(offs + (size_t)i * (NN + 1), elist + (size_t)i * NE,
                                       s_arr, d_arr, hbuf, bg + i * 256, xibuf);
    gemm256<1><<<GB, 256, 0, stream>>>(xibuf, WT + (size_t)(3 + i) * 65536, bs + i * 256,
                                       nullptr, nullptr, nullptr, nullptr, nullptr, nullptr,
                                       gs + i * 256, betas + i * 256, sw, i, comb, 0, NN);
  }
  gemm256<2><<<GB, 256, 0, stream>>>(comb, WT + (size_t)7 * 65536, bfv,
                                     nullptr, out, nullptr, nullptr, nullptr, nullptr,
                                     gf, betaf, nullptr, 0, nullptr, 0, NN);
}